// Round 1
// baseline (1476.451 us; speedup 1.0000x reference)
//
#include <hip/hip_runtime.h>
#include <cstdint>
#include <cstddef>

#define BATCH   65536
#define RANK_K  32769   // sorted_desc[32768] == 32769-th largest (1-indexed)

// ============ big GEMM (layers 1&2): C = relu((A*rowmask) @ B + bias), + per-row sum-of-squares partials ============
// BM=128, BN=128, BK=16, 256 threads, 8x8 per thread. Deterministic norm partials (fixed reduction order).
template<bool MASKED>
__global__ __launch_bounds__(256)
void gemm_relu_norm(const float* __restrict__ A, const float* __restrict__ B,
                    const float* __restrict__ bias, const float* __restrict__ mask,
                    float* __restrict__ C, float* __restrict__ normPart,
                    const int N, const int K)
{
    __shared__ float As[16][132];   // [k][row], padded stride 132 -> conflict-free
    __shared__ float Bs[16][132];   // [k][col]
    __shared__ float red[128][17];  // row-norm partial reduction

    const int t    = threadIdx.x;
    const int tx   = t & 15;
    const int ty   = t >> 4;
    const int row0 = blockIdx.x * 128;
    const int col0 = blockIdx.y * 128;

    // A-load mapping: 128 rows x 16 k per iter; 2 threads/row, 8 k each
    const int lrow = t >> 1;
    const int lk   = (t & 1) * 8;
    // B-load mapping: 16 k x 128 cols; 16 threads/k-row, 8 cols each
    const int bkk  = t >> 4;
    const int bcol = (t & 15) * 8;

    float scale = 1.0f;
    if (MASKED) scale = mask[row0 + lrow];

    const float* Aptr = A + (size_t)(row0 + lrow) * K + lk;
    const float* Bptr = B + (size_t)bkk * N + col0 + bcol;

    float acc[8][8];
    #pragma unroll
    for (int i = 0; i < 8; ++i)
        #pragma unroll
        for (int j = 0; j < 8; ++j) acc[i][j] = 0.0f;

    for (int k0 = 0; k0 < K; k0 += 16) {
        float4 a0 = *(const float4*)(Aptr + k0);
        float4 a1 = *(const float4*)(Aptr + k0 + 4);
        float4 b0 = *(const float4*)(Bptr + (size_t)k0 * N);
        float4 b1 = *(const float4*)(Bptr + (size_t)k0 * N + 4);
        if (MASKED) {
            a0.x *= scale; a0.y *= scale; a0.z *= scale; a0.w *= scale;
            a1.x *= scale; a1.y *= scale; a1.z *= scale; a1.w *= scale;
        }
        As[lk+0][lrow] = a0.x; As[lk+1][lrow] = a0.y;
        As[lk+2][lrow] = a0.z; As[lk+3][lrow] = a0.w;
        As[lk+4][lrow] = a1.x; As[lk+5][lrow] = a1.y;
        As[lk+6][lrow] = a1.z; As[lk+7][lrow] = a1.w;
        *(float4*)&Bs[bkk][bcol]     = b0;
        *(float4*)&Bs[bkk][bcol + 4] = b1;
        __syncthreads();
        #pragma unroll
        for (int kk = 0; kk < 16; ++kk) {
            float a_[8], b_[8];
            *(float4*)&a_[0] = *(const float4*)&As[kk][ty*8];
            *(float4*)&a_[4] = *(const float4*)&As[kk][ty*8 + 4];
            *(float4*)&b_[0] = *(const float4*)&Bs[kk][tx*8];
            *(float4*)&b_[4] = *(const float4*)&Bs[kk][tx*8 + 4];
            #pragma unroll
            for (int i = 0; i < 8; ++i)
                #pragma unroll
                for (int j = 0; j < 8; ++j)
                    acc[i][j] = fmaf(a_[i], b_[j], acc[i][j]);
        }
        __syncthreads();
    }

    float bv[8];
    #pragma unroll
    for (int j = 0; j < 8; ++j) bv[j] = bias[col0 + tx*8 + j];

    float rowsum[8];
    #pragma unroll
    for (int i = 0; i < 8; ++i) {
        float s = 0.0f;
        #pragma unroll
        for (int j = 0; j < 8; ++j) {
            float v = fmaxf(acc[i][j] + bv[j], 0.0f);   // dot first, then +bias, then relu (matches ref)
            acc[i][j] = v;
            s = fmaf(v, v, s);
        }
        rowsum[i] = s;
    }

    #pragma unroll
    for (int i = 0; i < 8; ++i) {
        const size_t row = (size_t)(row0 + ty*8 + i);
        *(float4*)&C[row * N + col0 + tx*8]     = *(float4*)&acc[i][0];
        *(float4*)&C[row * N + col0 + tx*8 + 4] = *(float4*)&acc[i][4];
    }

    #pragma unroll
    for (int i = 0; i < 8; ++i) red[ty*8 + i][tx] = rowsum[i];
    __syncthreads();
    if (t < 128) {
        float s = 0.0f;
        #pragma unroll
        for (int x = 0; x < 16; ++x) s += red[t][x];    // fixed order -> deterministic
        normPart[(size_t)blockIdx.y * BATCH + row0 + t] = s;
    }
}

// ============ deterministic partial-sum -> norm (sqrt in double = correctly-rounded fp32 sqrt) ============
__global__ __launch_bounds__(256)
void reduce_norms_kernel(const float* __restrict__ part, float* __restrict__ norms, const int nPart)
{
    const int i = blockIdx.x * 256 + threadIdx.x;
    float s = 0.0f;
    for (int p = 0; p < nPart; ++p) s += part[(size_t)p * BATCH + i];
    norms[i] = (float)sqrt((double)s);
}

// ============ exact 32769-th-largest radix select + mask write (single workgroup) ============
__global__ __launch_bounds__(1024)
void select_kernel(const float* __restrict__ norms, float* __restrict__ maskOut,
                   float* __restrict__ thrOut)
{
    __shared__ unsigned hist[2048];
    __shared__ unsigned sup[64];
    __shared__ unsigned shPrefix;
    __shared__ int      shRank;

    const int t = threadIdx.x;
    unsigned key[64];
    #pragma unroll
    for (int i = 0; i < 64; ++i) key[i] = __float_as_uint(norms[i * 1024 + t]);  // nonneg -> monotone

    unsigned prefix = 0;
    int rank = RANK_K;

    for (int pass = 0; pass < 3; ++pass) {
        const int      shift = (pass == 0) ? 21 : (pass == 1) ? 10 : 0;
        const unsigned nb    = (pass == 2) ? 1024u : 2048u;
        const unsigned pmask = (pass == 0) ? 0u : (pass == 1) ? 0xFFE00000u : 0xFFFFFC00u;

        hist[t] = 0; hist[t + 1024] = 0;
        __syncthreads();
        #pragma unroll
        for (int i = 0; i < 64; ++i) {
            const unsigned k = key[i];
            if ((k & pmask) == prefix)
                atomicAdd(&hist[(k >> shift) & (nb - 1u)], 1u);
        }
        __syncthreads();
        if (t < 64) {
            unsigned s = 0;
            #pragma unroll
            for (int j = 0; j < 32; ++j) s += hist[t * 32 + j];
            sup[t] = s;
        }
        __syncthreads();
        if (t == 0) {
            int cum = 0;
            int sb;
            for (sb = 63; sb >= 0; --sb) {               // guaranteed hit: candidates >= rank
                if (cum + (int)sup[sb] >= rank) break;
                cum += (int)sup[sb];
            }
            int b;
            for (b = sb * 32 + 31; b >= sb * 32; --b) {
                if (cum + (int)hist[b] >= rank) break;
                cum += (int)hist[b];
            }
            shRank   = rank - cum;
            shPrefix = prefix | ((unsigned)b << shift);
        }
        __syncthreads();
        prefix = shPrefix;
        rank   = shRank;
        __syncthreads();
    }

    if (t == 0) thrOut[0] = __uint_as_float(prefix);
    #pragma unroll
    for (int i = 0; i < 64; ++i)
        maskOut[i * 1024 + t] = (key[i] > prefix) ? 1.0f : 0.0f;   // strict > like reference
}

// ============ layer 3: h3 = relu((h2*m2) @ W3[256x10] + b3), full row norms ============
__global__ __launch_bounds__(256)
void layer3_kernel(const float* __restrict__ h2, const float* __restrict__ W3,
                   const float* __restrict__ b3, const float* __restrict__ mask2,
                   float* __restrict__ h3, float* __restrict__ norms3)
{
    __shared__ float wT[10][260];   // transposed W3 for b128 broadcast reads
    __shared__ float red[64][5];

    const int t    = threadIdx.x;
    const int r    = t & 63;
    const int g    = t >> 6;          // 0..3 column groups (3,3,3,1)
    const int j0   = g * 3;
    const int nj   = (g == 3) ? 1 : 3;
    const int row0 = blockIdx.x * 64;
    const int row  = row0 + r;

    for (int e = t; e < 2560; e += 256) wT[e % 10][e / 10] = W3[e];
    __syncthreads();

    const float m = mask2[row];
    const float* hrow = h2 + (size_t)row * 256;

    float acc[3] = {0.0f, 0.0f, 0.0f};
    for (int k = 0; k < 256; k += 4) {
        float4 v = *(const float4*)(hrow + k);
        v.x *= m; v.y *= m; v.z *= m; v.w *= m;
        float4 w0 = *(const float4*)&wT[j0][k];
        acc[0] += v.x*w0.x + v.y*w0.y + v.z*w0.z + v.w*w0.w;
        if (nj > 1) {
            float4 w1 = *(const float4*)&wT[j0+1][k];
            acc[1] += v.x*w1.x + v.y*w1.y + v.z*w1.z + v.w*w1.w;
            float4 w2 = *(const float4*)&wT[j0+2][k];
            acc[2] += v.x*w2.x + v.y*w2.y + v.z*w2.z + v.w*w2.w;
        }
    }

    float ss = 0.0f;
    for (int jj = 0; jj < nj; ++jj) {
        float v = fmaxf(acc[jj] + b3[j0 + jj], 0.0f);
        h3[(size_t)row * 10 + j0 + jj] = v;
        ss += v * v;
    }
    red[r][g] = ss;
    __syncthreads();
    if (t < 64) {
        float s = red[t][0] + red[t][1] + red[t][2] + red[t][3];  // fixed order
        norms3[row0 + t] = (float)sqrt((double)s);
    }
}

// ============ layer 4: h4 = (h3*m3) @ W4[10x10] + b4 (no relu), norms ============
__global__ __launch_bounds__(256)
void layer4_kernel(const float* __restrict__ h3, const float* __restrict__ W4,
                   const float* __restrict__ b4, const float* __restrict__ mask3,
                   float* __restrict__ h4, float* __restrict__ norms4)
{
    __shared__ float w[100];
    __shared__ float bb[10];
    const int t = threadIdx.x;
    if (t < 100) w[t] = W4[t];
    if (t < 10)  bb[t] = b4[t];
    __syncthreads();

    const int row = blockIdx.x * 256 + t;
    const float m = mask3[row];
    const float* hr = h3 + (size_t)row * 10;
    float v[10];
    #pragma unroll
    for (int k = 0; k < 10; ++k) v[k] = hr[k] * m;

    float s = 0.0f;
    #pragma unroll
    for (int j = 0; j < 10; ++j) {
        float a = 0.0f;
        #pragma unroll
        for (int k = 0; k < 10; ++k) a = fmaf(v[k], w[k*10 + j], a);
        a += bb[j];                     // dot then +bias (matches ref)
        h4[(size_t)row * 10 + j] = a;
        s = fmaf(a, a, s);
    }
    norms4[row] = (float)sqrt((double)s);
}

// ============ final: out = softmax(h4 * m4) ============
__global__ __launch_bounds__(256)
void softmax_kernel(const float* __restrict__ h4, const float* __restrict__ mask4,
                    float* __restrict__ out)
{
    const int t   = threadIdx.x;
    const int row = blockIdx.x * 256 + t;
    const float m = mask4[row];
    const float* hr = h4 + (size_t)row * 10;
    float v[10];
    #pragma unroll
    for (int k = 0; k < 10; ++k) v[k] = hr[k] * m;
    float mx = v[0];
    #pragma unroll
    for (int k = 1; k < 10; ++k) mx = fmaxf(mx, v[k]);
    float e[10];
    float s = 0.0f;
    #pragma unroll
    for (int k = 0; k < 10; ++k) { e[k] = expf(v[k] - mx); s += e[k]; }
    const float inv = 1.0f / s;
    #pragma unroll
    for (int k = 0; k < 10; ++k) out[(size_t)row * 10 + k] = e[k] * inv;
}

extern "C" void kernel_launch(void* const* d_in, const int* in_sizes, int n_in,
                              void* d_out, int out_size, void* d_ws, size_t ws_size,
                              hipStream_t stream)
{
    const float* x  = (const float*)d_in[0];
    const float* W1 = (const float*)d_in[1];
    const float* b1 = (const float*)d_in[2];
    const float* W2 = (const float*)d_in[3];
    const float* b2 = (const float*)d_in[4];
    const float* W3 = (const float*)d_in[5];
    const float* b3 = (const float*)d_in[6];
    const float* W4 = (const float*)d_in[7];
    const float* b4 = (const float*)d_in[8];

    float* out = (float*)d_out;                 // [65536,10]
    float* m1  = out + (size_t)BATCH * 10;      // [65536] each
    float* m2  = m1 + BATCH;
    float* m3  = m2 + BATCH;
    float* m4  = m3 + BATCH;

    float* ws    = (float*)d_ws;
    float* h1    = ws;                                  // 65536*512
    float* h2    = h1 + (size_t)BATCH * 512;            // 65536*256
    float* h3    = h2 + (size_t)BATCH * 256;            // 65536*10
    float* h4    = h3 + (size_t)BATCH * 10;             // 65536*10
    float* n1    = h4 + (size_t)BATCH * 10;             // 65536 x4
    float* n2    = n1 + BATCH;
    float* n3    = n2 + BATCH;
    float* n4    = n3 + BATCH;
    float* part  = n4 + BATCH;                          // 4*65536
    float* thr   = part + (size_t)4 * BATCH;            // 4

    // layer 1: x[65536,784] @ W1[784,512]
    gemm_relu_norm<false><<<dim3(512, 4), 256, 0, stream>>>(x, W1, b1, nullptr, h1, part, 512, 784);
    reduce_norms_kernel<<<256, 256, 0, stream>>>(part, n1, 4);
    select_kernel<<<1, 1024, 0, stream>>>(n1, m1, thr + 0);

    // layer 2: (h1*m1)[65536,512] @ W2[512,256]
    gemm_relu_norm<true><<<dim3(512, 2), 256, 0, stream>>>(h1, W2, b2, m1, h2, part, 256, 512);
    reduce_norms_kernel<<<256, 256, 0, stream>>>(part, n2, 2);
    select_kernel<<<1, 1024, 0, stream>>>(n2, m2, thr + 1);

    // layer 3: (h2*m2)[65536,256] @ W3[256,10]
    layer3_kernel<<<1024, 256, 0, stream>>>(h2, W3, b3, m2, h3, n3);
    select_kernel<<<1, 1024, 0, stream>>>(n3, m3, thr + 2);

    // layer 4: (h3*m3)[65536,10] @ W4[10,10] (no relu)
    layer4_kernel<<<256, 256, 0, stream>>>(h3, W4, b4, m3, h4, n4);
    select_kernel<<<1, 1024, 0, stream>>>(n4, m4, thr + 3);

    // softmax(h4*m4)
    softmax_kernel<<<256, 256, 0, stream>>>(h4, m4, out);
}

// Round 2
// 1230.241 us; speedup vs baseline: 1.2001x; 1.2001x over previous
//
#include <hip/hip_runtime.h>
#include <cstdint>
#include <cstddef>

#define BATCH   65536
#define RANK_K  32769   // sorted_desc[32768] == 32769-th largest (1-indexed)

// ============ big GEMM (layers 1&2): C = relu((A*rowmask) @ B + bias), + per-row sum-of-squares partials ============
// BM=256, BN=128, BK=16, 256 threads, 16x8 per thread (0.75 B LDS per FMA -> ~89% FMA ceiling).
// FMA chain order per output element is IDENTICAL to the validated round-1 kernel (k ascending,
// single-register chain, bias->relu->square->16-group row reduction in same order) -> bit-identical results.
template<bool MASKED>
__global__ __launch_bounds__(256, 2)
void gemm_relu_norm(const float* __restrict__ A, const float* __restrict__ B,
                    const float* __restrict__ bias, const float* __restrict__ mask,
                    float* __restrict__ C, float* __restrict__ normPart,
                    const int N, const int K)
{
    __shared__ float As[16][260];   // [k][row], padded
    __shared__ float Bs[16][136];   // [k][col], padded
    __shared__ float red[256][17];  // row-norm partial reduction

    const int t    = threadIdx.x;
    const int tr   = t >> 4;          // 0..15 row group (16 rows each)
    const int tc   = t & 15;          // 0..15 col group (8 cols each)
    const int row0 = blockIdx.x * 256;
    const int col0 = blockIdx.y * 128;

    // A-load: thread t loads row (row0+t), 16 consecutive k per tile (one 64B line)
    const float* Aptr = A + (size_t)(row0 + t) * K;
    // B-load: 16 k-rows x 128 cols; thread: k=t>>4, cols (t&15)*8..+7
    const int bk = t >> 4;
    const int bc = (t & 15) * 8;
    const float* Bptr = B + (size_t)bk * N + col0 + bc;

    float scale = 1.0f;
    if (MASKED) scale = mask[row0 + t];

    float acc[16][8];
    #pragma unroll
    for (int i = 0; i < 16; ++i)
        #pragma unroll
        for (int j = 0; j < 8; ++j) acc[i][j] = 0.0f;

    for (int k0 = 0; k0 < K; k0 += 16) {
        float4 a0 = *(const float4*)(Aptr + k0);
        float4 a1 = *(const float4*)(Aptr + k0 + 4);
        float4 a2 = *(const float4*)(Aptr + k0 + 8);
        float4 a3 = *(const float4*)(Aptr + k0 + 12);
        float4 b0 = *(const float4*)(Bptr + (size_t)k0 * N);
        float4 b1 = *(const float4*)(Bptr + (size_t)k0 * N + 4);
        if (MASKED) {
            a0.x *= scale; a0.y *= scale; a0.z *= scale; a0.w *= scale;
            a1.x *= scale; a1.y *= scale; a1.z *= scale; a1.w *= scale;
            a2.x *= scale; a2.y *= scale; a2.z *= scale; a2.w *= scale;
            a3.x *= scale; a3.y *= scale; a3.z *= scale; a3.w *= scale;
        }
        As[ 0][t] = a0.x; As[ 1][t] = a0.y; As[ 2][t] = a0.z; As[ 3][t] = a0.w;
        As[ 4][t] = a1.x; As[ 5][t] = a1.y; As[ 6][t] = a1.z; As[ 7][t] = a1.w;
        As[ 8][t] = a2.x; As[ 9][t] = a2.y; As[10][t] = a2.z; As[11][t] = a2.w;
        As[12][t] = a3.x; As[13][t] = a3.y; As[14][t] = a3.z; As[15][t] = a3.w;
        *(float4*)&Bs[bk][bc]     = b0;
        *(float4*)&Bs[bk][bc + 4] = b1;
        __syncthreads();
        #pragma unroll
        for (int kk = 0; kk < 16; ++kk) {
            float a_[16], b_[8];
            *(float4*)&a_[0]  = *(const float4*)&As[kk][tr*16];
            *(float4*)&a_[4]  = *(const float4*)&As[kk][tr*16 + 4];
            *(float4*)&a_[8]  = *(const float4*)&As[kk][tr*16 + 8];
            *(float4*)&a_[12] = *(const float4*)&As[kk][tr*16 + 12];
            *(float4*)&b_[0]  = *(const float4*)&Bs[kk][tc*8];
            *(float4*)&b_[4]  = *(const float4*)&Bs[kk][tc*8 + 4];
            #pragma unroll
            for (int i = 0; i < 16; ++i)
                #pragma unroll
                for (int j = 0; j < 8; ++j)
                    acc[i][j] = fmaf(a_[i], b_[j], acc[i][j]);
        }
        __syncthreads();
    }

    float bv[8];
    #pragma unroll
    for (int j = 0; j < 8; ++j) bv[j] = bias[col0 + tc*8 + j];

    float rowsum[16];
    #pragma unroll
    for (int i = 0; i < 16; ++i) {
        float s = 0.0f;
        #pragma unroll
        for (int j = 0; j < 8; ++j) {
            float v = fmaxf(acc[i][j] + bv[j], 0.0f);   // dot, +bias, relu (matches ref)
            acc[i][j] = v;
            s = fmaf(v, v, s);
        }
        rowsum[i] = s;
    }

    #pragma unroll
    for (int i = 0; i < 16; ++i) {
        const size_t row = (size_t)(row0 + tr*16 + i);
        *(float4*)&C[row * N + col0 + tc*8]     = *(float4*)&acc[i][0];
        *(float4*)&C[row * N + col0 + tc*8 + 4] = *(float4*)&acc[i][4];
    }

    #pragma unroll
    for (int i = 0; i < 16; ++i) red[tr*16 + i][tc] = rowsum[i];
    __syncthreads();
    {
        float s = 0.0f;
        #pragma unroll
        for (int x = 0; x < 16; ++x) s += red[t][x];    // fixed order -> deterministic
        normPart[(size_t)blockIdx.y * BATCH + row0 + t] = s;
    }
}

// ============ deterministic partial-sum -> norm (sqrt in double = correctly-rounded fp32 sqrt) ============
__global__ __launch_bounds__(256)
void reduce_norms_kernel(const float* __restrict__ part, float* __restrict__ norms, const int nPart)
{
    const int i = blockIdx.x * 256 + threadIdx.x;
    float s = 0.0f;
    for (int p = 0; p < nPart; ++p) s += part[(size_t)p * BATCH + i];
    norms[i] = (float)sqrt((double)s);
}

// ============ exact 32769-th-largest via binary search on uint key space (no atomics) ============
__global__ __launch_bounds__(1024)
void select_kernel(const float* __restrict__ norms, float* __restrict__ maskOut,
                   float* __restrict__ thrOut)
{
    __shared__ int wsum[16];

    const int t = threadIdx.x;
    unsigned key[64];
    const float4* n4 = (const float4*)norms;
    #pragma unroll
    for (int i = 0; i < 16; ++i) {
        float4 v = n4[i * 1024 + t];
        key[i*4+0] = __float_as_uint(v.x);
        key[i*4+1] = __float_as_uint(v.y);
        key[i*4+2] = __float_as_uint(v.z);
        key[i*4+3] = __float_as_uint(v.w);      // nonneg floats -> monotone uint order
    }

    // V = min{ T : count(key > T) < RANK_K }  == exact RANK_K-th largest value
    unsigned lo = 0u, hi = 0x7F800000u;
    while (lo < hi) {                            // uniform across all threads
        const unsigned mid = lo + ((hi - lo) >> 1);
        int c = 0;
        #pragma unroll
        for (int i = 0; i < 64; ++i) c += (key[i] > mid) ? 1 : 0;
        #pragma unroll
        for (int off = 32; off > 0; off >>= 1) c += __shfl_down(c, off, 64);
        if ((t & 63) == 0) wsum[t >> 6] = c;
        __syncthreads();
        int total = 0;
        #pragma unroll
        for (int w = 0; w < 16; ++w) total += wsum[w];
        if (total < RANK_K) hi = mid; else lo = mid + 1;
        __syncthreads();
    }

    if (t == 0) thrOut[0] = __uint_as_float(lo);
    float4* m4 = (float4*)maskOut;
    #pragma unroll
    for (int i = 0; i < 16; ++i) {
        float4 m;
        m.x = (key[i*4+0] > lo) ? 1.0f : 0.0f;
        m.y = (key[i*4+1] > lo) ? 1.0f : 0.0f;
        m.z = (key[i*4+2] > lo) ? 1.0f : 0.0f;
        m.w = (key[i*4+3] > lo) ? 1.0f : 0.0f;   // strict > like reference
        m4[i * 1024 + t] = m;
    }
}

// ============ layer 3: h3 = relu((h2*m2) @ W3[256x10] + b3), full row norms ============
__global__ __launch_bounds__(256)
void layer3_kernel(const float* __restrict__ h2, const float* __restrict__ W3,
                   const float* __restrict__ b3, const float* __restrict__ mask2,
                   float* __restrict__ h3, float* __restrict__ norms3)
{
    __shared__ float wT[10][260];   // transposed W3 for b128 broadcast reads
    __shared__ float red[64][5];

    const int t    = threadIdx.x;
    const int r    = t & 63;
    const int g    = t >> 6;          // 0..3 column groups (3,3,3,1)
    const int j0   = g * 3;
    const int nj   = (g == 3) ? 1 : 3;
    const int row0 = blockIdx.x * 64;
    const int row  = row0 + r;

    for (int e = t; e < 2560; e += 256) wT[e % 10][e / 10] = W3[e];
    __syncthreads();

    const float m = mask2[row];
    const float* hrow = h2 + (size_t)row * 256;

    float acc[3] = {0.0f, 0.0f, 0.0f};
    for (int k = 0; k < 256; k += 4) {
        float4 v = *(const float4*)(hrow + k);
        v.x *= m; v.y *= m; v.z *= m; v.w *= m;
        float4 w0 = *(const float4*)&wT[j0][k];
        acc[0] += v.x*w0.x + v.y*w0.y + v.z*w0.z + v.w*w0.w;
        if (nj > 1) {
            float4 w1 = *(const float4*)&wT[j0+1][k];
            acc[1] += v.x*w1.x + v.y*w1.y + v.z*w1.z + v.w*w1.w;
            float4 w2 = *(const float4*)&wT[j0+2][k];
            acc[2] += v.x*w2.x + v.y*w2.y + v.z*w2.z + v.w*w2.w;
        }
    }

    float ss = 0.0f;
    for (int jj = 0; jj < nj; ++jj) {
        float v = fmaxf(acc[jj] + b3[j0 + jj], 0.0f);
        h3[(size_t)row * 10 + j0 + jj] = v;
        ss += v * v;
    }
    red[r][g] = ss;
    __syncthreads();
    if (t < 64) {
        float s = red[t][0] + red[t][1] + red[t][2] + red[t][3];  // fixed order
        norms3[row0 + t] = (float)sqrt((double)s);
    }
}

// ============ layer 4: h4 = (h3*m3) @ W4[10x10] + b4 (no relu), norms ============
__global__ __launch_bounds__(256)
void layer4_kernel(const float* __restrict__ h3, const float* __restrict__ W4,
                   const float* __restrict__ b4, const float* __restrict__ mask3,
                   float* __restrict__ h4, float* __restrict__ norms4)
{
    __shared__ float w[100];
    __shared__ float bb[10];
    const int t = threadIdx.x;
    if (t < 100) w[t] = W4[t];
    if (t < 10)  bb[t] = b4[t];
    __syncthreads();

    const int row = blockIdx.x * 256 + t;
    const float m = mask3[row];
    const float* hr = h3 + (size_t)row * 10;
    float v[10];
    #pragma unroll
    for (int k = 0; k < 10; ++k) v[k] = hr[k] * m;

    float s = 0.0f;
    #pragma unroll
    for (int j = 0; j < 10; ++j) {
        float a = 0.0f;
        #pragma unroll
        for (int k = 0; k < 10; ++k) a = fmaf(v[k], w[k*10 + j], a);
        a += bb[j];                     // dot then +bias (matches ref)
        h4[(size_t)row * 10 + j] = a;
        s = fmaf(a, a, s);
    }
    norms4[row] = (float)sqrt((double)s);
}

// ============ final: out = softmax(h4 * m4) ============
__global__ __launch_bounds__(256)
void softmax_kernel(const float* __restrict__ h4, const float* __restrict__ mask4,
                    float* __restrict__ out)
{
    const int t   = threadIdx.x;
    const int row = blockIdx.x * 256 + t;
    const float m = mask4[row];
    const float* hr = h4 + (size_t)row * 10;
    float v[10];
    #pragma unroll
    for (int k = 0; k < 10; ++k) v[k] = hr[k] * m;
    float mx = v[0];
    #pragma unroll
    for (int k = 1; k < 10; ++k) mx = fmaxf(mx, v[k]);
    float e[10];
    float s = 0.0f;
    #pragma unroll
    for (int k = 0; k < 10; ++k) { e[k] = expf(v[k] - mx); s += e[k]; }
    const float inv = 1.0f / s;
    #pragma unroll
    for (int k = 0; k < 10; ++k) out[(size_t)row * 10 + k] = e[k] * inv;
}

extern "C" void kernel_launch(void* const* d_in, const int* in_sizes, int n_in,
                              void* d_out, int out_size, void* d_ws, size_t ws_size,
                              hipStream_t stream)
{
    const float* x  = (const float*)d_in[0];
    const float* W1 = (const float*)d_in[1];
    const float* b1 = (const float*)d_in[2];
    const float* W2 = (const float*)d_in[3];
    const float* b2 = (const float*)d_in[4];
    const float* W3 = (const float*)d_in[5];
    const float* b3 = (const float*)d_in[6];
    const float* W4 = (const float*)d_in[7];
    const float* b4 = (const float*)d_in[8];

    float* out = (float*)d_out;                 // [65536,10]
    float* m1  = out + (size_t)BATCH * 10;      // [65536] each
    float* m2  = m1 + BATCH;
    float* m3  = m2 + BATCH;
    float* m4  = m3 + BATCH;

    float* ws    = (float*)d_ws;
    float* h1    = ws;                                  // 65536*512
    float* h2    = h1 + (size_t)BATCH * 512;            // 65536*256
    float* h3    = h2 + (size_t)BATCH * 256;            // 65536*10
    float* h4    = h3 + (size_t)BATCH * 10;             // 65536*10
    float* n1    = h4 + (size_t)BATCH * 10;             // 65536 x4
    float* n2    = n1 + BATCH;
    float* n3    = n2 + BATCH;
    float* n4    = n3 + BATCH;
    float* part  = n4 + BATCH;                          // 4*65536
    float* thr   = part + (size_t)4 * BATCH;            // 4

    // layer 1: x[65536,784] @ W1[784,512]
    gemm_relu_norm<false><<<dim3(256, 4), 256, 0, stream>>>(x, W1, b1, nullptr, h1, part, 512, 784);
    reduce_norms_kernel<<<256, 256, 0, stream>>>(part, n1, 4);
    select_kernel<<<1, 1024, 0, stream>>>(n1, m1, thr + 0);

    // layer 2: (h1*m1)[65536,512] @ W2[512,256]
    gemm_relu_norm<true><<<dim3(256, 2), 256, 0, stream>>>(h1, W2, b2, m1, h2, part, 256, 512);
    reduce_norms_kernel<<<256, 256, 0, stream>>>(part, n2, 2);
    select_kernel<<<1, 1024, 0, stream>>>(n2, m2, thr + 1);

    // layer 3: (h2*m2)[65536,256] @ W3[256,10]
    layer3_kernel<<<1024, 256, 0, stream>>>(h2, W3, b3, m2, h3, n3);
    select_kernel<<<1, 1024, 0, stream>>>(n3, m3, thr + 2);

    // layer 4: (h3*m3)[65536,10] @ W4[10,10] (no relu)
    layer4_kernel<<<256, 256, 0, stream>>>(h3, W4, b4, m3, h4, n4);
    select_kernel<<<1, 1024, 0, stream>>>(n4, m4, thr + 3);

    // softmax(h4*m4)
    softmax_kernel<<<256, 256, 0, stream>>>(h4, m4, out);
}